// Round 5
// baseline (256.123 us; speedup 1.0000x reference)
//
#include <hip/hip_runtime.h>
#include <hip/hip_cooperative_groups.h>
namespace cg = cooperative_groups;

#define B_    32
#define S_    64
#define D_    8
#define NE_   512        // S_*D_
#define E_    150000
#define CAP   512        // payload slots per eidx bin (mean 293)
#define CHUNK 293        // ceil(E_/512) edges scattered per block

// ws layout: cursor[NE_] int, then payload[NE_*CAP] int.

__global__ __launch_bounds__(256, 2)
void fused_kernel(const float* __restrict__ nf,
                  const float* __restrict__ iw0, const float* __restrict__ ib0,
                  const float* __restrict__ iw1, const float* __restrict__ ib1,
                  const float* __restrict__ ow0, const float* __restrict__ ob0,
                  const float* __restrict__ ow1, const float* __restrict__ ob1,
                  const int* __restrict__ inc,
                  int* __restrict__ cursor, int* __restrict__ payload,
                  float* __restrict__ out)
{
    const int bid = blockIdx.x;          // == eidx in phase 2
    const int tid = threadIdx.x;
    cg::grid_group grid = cg::this_grid();

    __shared__ int lcount[NE_];
    __shared__ int lbase[NE_];
    __shared__ float hbuf[4][64];              // per-wave h staging
    __shared__ float acc[32][33];              // per-batch sums (+1 pad)
    __shared__ float hb[32][33];               // out-MLP hidden
    __shared__ float cnts[32];
    __shared__ __align__(16) float q0s[1024];  // out_core0[eidx] (32x32)
    __shared__ __align__(16) float q1s[512];   // out_core1[eidx] (16x32)
    __shared__ float qb0s[32], qb1s[16];

    // ---- phase 0: zero global cursor + local histogram ----
    if (bid < 2) cursor[bid * 256 + tid] = 0;
    for (int i = tid; i < NE_; i += 256) lcount[i] = 0;
    __syncthreads();
    grid.sync();

    // ---- phase 1: LDS-aggregated scatter of slice [bid*CHUNK, end) ----
    {
        const int start = bid * CHUNK;
        const int end   = min(start + CHUNK, E_);
        int ei0 = -1, lp0 = 0, pl0 = 0;
        int ei1 = -1, lp1 = 0, pl1 = 0;
        int e = start + tid;
        if (e < end) {
            const int4 c = ((const int4*)inc)[e];   // c0=batch c1=node c2 c3
            ei0 = c.z * D_ + c.w;
            pl0 = (c.x << 16) | (c.y * S_ + c.z);
            lp0 = atomicAdd(&lcount[ei0], 1);
        }
        e = start + 256 + tid;
        if (e < end) {
            const int4 c = ((const int4*)inc)[e];
            ei1 = c.z * D_ + c.w;
            pl1 = (c.x << 16) | (c.y * S_ + c.z);
            lp1 = atomicAdd(&lcount[ei1], 1);
        }
        __syncthreads();
        for (int i = tid; i < NE_; i += 256) {
            const int c = lcount[i];
            lbase[i] = (c > 0) ? atomicAdd(&cursor[i], c) : 0;
        }
        __syncthreads();
        if (ei0 >= 0) {
            const int idx = lbase[ei0] + lp0;
            if (idx < CAP) payload[ei0 * CAP + idx] = pl0;
        }
        if (ei1 >= 0) {
            const int idx = lbase[ei1] + lp1;
            if (idx < CAP) payload[ei1 * CAP + idx] = pl1;
        }
    }
    grid.sync();

    // ---- phase 2: per-eidx MLP + segment mean + out-MLP ----
    const int lane = tid & 63;
    const int wav  = tid >> 6;
    const int slot = lane >> 5;    // which of 2 edges this lane serves
    const int o    = lane & 31;    // output neuron owned by this lane

    // persistent per-lane in-MLP weights (never re-fetched)
    float w0r[16], w1r[32];
    #pragma unroll
    for (int j = 0; j < 4; ++j) {
        float4 v = ((const float4*)(iw0 + (size_t)bid * 512 + o * 16))[j];
        w0r[4*j] = v.x; w0r[4*j+1] = v.y; w0r[4*j+2] = v.z; w0r[4*j+3] = v.w;
    }
    #pragma unroll
    for (int j = 0; j < 8; ++j) {
        float4 v = ((const float4*)(iw1 + (size_t)bid * 1024 + o * 32))[j];
        w1r[4*j] = v.x; w1r[4*j+1] = v.y; w1r[4*j+2] = v.z; w1r[4*j+3] = v.w;
    }
    const float b0r = ib0[bid * 32 + o];
    const float b1r = ib1[bid * 32 + o];

    // stage out-MLP weights + zero accumulators
    for (int i = tid; i < 1024; i += 256) q0s[i] = ow0[(size_t)bid * 1024 + i];
    for (int i = tid; i < 512;  i += 256) q1s[i] = ow1[(size_t)bid * 512 + i];
    if (tid < 32) { qb0s[tid] = ob0[bid * 32 + tid]; cnts[tid] = 0.f; }
    else if (tid < 48) qb1s[tid - 32] = ob1[bid * 16 + (tid - 32)];
    for (int i = tid; i < 32 * 33; i += 256) ((float*)acc)[i] = 0.f;
    __syncthreads();

    const int n = min(cursor[bid], CAP);
    for (int i = wav * 2 + slot; i < n; i += 8) {
        const int p   = payload[bid * CAP + i];
        const int b   = p >> 16;
        const int row = p & 0xFFFF;

        float x[16];
        #pragma unroll
        for (int j = 0; j < 4; ++j) {
            float4 v = ((const float4*)(nf + (size_t)row * 16))[j];
            x[4*j] = v.x; x[4*j+1] = v.y; x[4*j+2] = v.z; x[4*j+3] = v.w;
        }
        float h = b0r;
        #pragma unroll
        for (int k = 0; k < 16; ++k) h = fmaf(w0r[k], x[k], h);
        h = fmaxf(h, 0.f);

        hbuf[wav][slot * 32 + o] = h;          // same-wave LDS, in-order
        __builtin_amdgcn_wave_barrier();
        float a = b1r;
        #pragma unroll
        for (int j = 0; j < 8; ++j) {
            float4 v = ((const float4*)&hbuf[wav][slot * 32])[j];
            a = fmaf(w1r[4*j],   v.x, a); a = fmaf(w1r[4*j+1], v.y, a);
            a = fmaf(w1r[4*j+2], v.z, a); a = fmaf(w1r[4*j+3], v.w, a);
        }
        __builtin_amdgcn_wave_barrier();
        a = fmaxf(a, 0.f);

        atomicAdd(&acc[b][o], a);              // (b+o)%32 banks: conflict-free
        if (o == 0) atomicAdd(&cnts[b], 1.f);
    }
    __syncthreads();

    // mean + out layer 0: thread t -> batch b = t>>3, outputs 4*(t&7)..
    {
        const int b  = tid >> 3;
        const int o0 = (tid & 7) * 4;
        const float cv  = cnts[b];
        const float inv = cv > 0.f ? 1.0f / cv : 0.0f;
        #pragma unroll
        for (int j = 0; j < 4; ++j) {
            const int oo = o0 + j;
            float d = 0.f;
            #pragma unroll
            for (int k = 0; k < 32; ++k) d = fmaf(q0s[oo * 32 + k], acc[b][k], d);
            hb[b][oo] = fmaxf(fmaf(d, inv, qb0s[oo]), 0.f);
        }
    }
    __syncthreads();

    // out layer 1: thread t -> batch b = t>>3, outputs 2*(t&7)..
    {
        const int b  = tid >> 3;
        const int o0 = (tid & 7) * 2;
        float r[2];
        #pragma unroll
        for (int j = 0; j < 2; ++j) {
            const int oo = o0 + j;
            float d = qb1s[oo];
            #pragma unroll
            for (int k = 0; k < 32; ++k) d = fmaf(q1s[oo * 32 + k], hb[b][k], d);
            r[j] = fmaxf(d, 0.f);
        }
        float2* op = (float2*)(out + ((size_t)b * NE_ + bid) * 16 + o0);
        *op = make_float2(r[0], r[1]);
    }
}

extern "C" void kernel_launch(void* const* d_in, const int* in_sizes, int n_in,
                              void* d_out, int out_size, void* d_ws, size_t ws_size,
                              hipStream_t stream) {
    const float* nf  = (const float*)d_in[0];
    const float* iw0 = (const float*)d_in[1];
    const float* ib0 = (const float*)d_in[2];
    const float* iw1 = (const float*)d_in[3];
    const float* ib1 = (const float*)d_in[4];
    const float* ow0 = (const float*)d_in[5];
    const float* ob0 = (const float*)d_in[6];
    const float* ow1 = (const float*)d_in[7];
    const float* ob1 = (const float*)d_in[8];
    const int*   inc = (const int*)d_in[9];

    int* cursor  = (int*)d_ws;
    int* payload = cursor + NE_;
    float* out   = (float*)d_out;

    void* args[] = { &nf, &iw0, &ib0, &iw1, &ib1, &ow0, &ob0, &ow1, &ob1,
                     &inc, &cursor, &payload, &out };
    hipLaunchCooperativeKernel((const void*)fused_kernel,
                               dim3(NE_), dim3(256), args, 0, stream);
}

// Round 6
// 128.862 us; speedup vs baseline: 1.9876x; 1.9876x over previous
//
#include <hip/hip_runtime.h>

#define B_    32
#define S_    64
#define D_    8
#define NE_   512        // S_*D_
#define E_    150000
#define CAP   512        // payload slots per eidx bin (mean 293)

// ws layout: cursor[NE_] int, then payload[NE_*CAP] int.

__global__ void zero_cursor(int* __restrict__ cursor) {
    cursor[threadIdx.x + blockIdx.x * 256] = 0;
}

__global__ __launch_bounds__(1024)
void scatter_kernel(const int* __restrict__ inc,
                    int* __restrict__ cursor,
                    int* __restrict__ payload) {
    __shared__ int lcount[NE_];
    __shared__ int lbase[NE_];
    const int tid = threadIdx.x;

    for (int i = tid; i < NE_; i += 1024) lcount[i] = 0;
    __syncthreads();

    const int e = blockIdx.x * 1024 + tid;
    int ei = -1, lp = 0, pl = 0;
    if (e < E_) {
        const int4 c = ((const int4*)inc)[e];   // c0=batch c1=node c2 c3
        ei = c.z * D_ + c.w;
        pl = (c.x << 16) | (c.y * S_ + c.z);
        lp = atomicAdd(&lcount[ei], 1);         // LDS atomic
    }
    __syncthreads();
    for (int i = tid; i < NE_; i += 1024) {
        const int c = lcount[i];
        lbase[i] = (c > 0) ? atomicAdd(&cursor[i], c) : 0;  // 1 global atomic/bin/block
    }
    __syncthreads();
    if (ei >= 0) {
        const int idx = lbase[ei] + lp;
        if (idx < CAP) payload[ei * CAP + idx] = pl;
    }
}

__global__ __launch_bounds__(512, 4)
void main_kernel(const float* __restrict__ nf,
                 const float* __restrict__ iw0, const float* __restrict__ ib0,
                 const float* __restrict__ iw1, const float* __restrict__ ib1,
                 const float* __restrict__ ow0, const float* __restrict__ ob0,
                 const float* __restrict__ ow1, const float* __restrict__ ob1,
                 const int* __restrict__ cursor, const int* __restrict__ payload,
                 float* __restrict__ out) {
    const int bid = blockIdx.x;          // == eidx
    const int tid = threadIdx.x;
    const int lane = tid & 63;
    const int wav  = tid >> 6;           // 0..7
    const int half = (tid >> 5) & 1;     // which edge-slot half of the wave
    const int o    = lane & 31;          // output neuron owned by this lane
    const int slot_id = wav * 2 + half;  // 0..15

    __shared__ float hbuf[8][64];              // per-wave h staging
    __shared__ float acc[32][33];              // per-batch sums (+1 pad)
    __shared__ float hb[32][33];               // out-MLP hidden
    __shared__ float cnts[32];
    __shared__ __align__(16) float q0s[1024];  // out_core0[eidx] (32x32)
    __shared__ __align__(16) float q1s[512];   // out_core1[eidx] (16x32)
    __shared__ float qb0s[32], qb1s[16];

    // ---- persistent per-lane in-MLP weights, PINNED in VGPRs ----
    float w0r[16], w1r[32];
    #pragma unroll
    for (int j = 0; j < 4; ++j) {
        float4 v = ((const float4*)(iw0 + (size_t)bid * 512 + o * 16))[j];
        w0r[4*j] = v.x; w0r[4*j+1] = v.y; w0r[4*j+2] = v.z; w0r[4*j+3] = v.w;
    }
    #pragma unroll
    for (int j = 0; j < 8; ++j) {
        float4 v = ((const float4*)(iw1 + (size_t)bid * 1024 + o * 32))[j];
        w1r[4*j] = v.x; w1r[4*j+1] = v.y; w1r[4*j+2] = v.z; w1r[4*j+3] = v.w;
    }
    float b0r = ib0[bid * 32 + o];
    float b1r = ib1[bid * 32 + o];
    // prevent the compiler from sinking/rematerializing these loads into the loop
    #pragma unroll
    for (int k = 0; k < 16; ++k) asm volatile("" : "+v"(w0r[k]));
    #pragma unroll
    for (int k = 0; k < 32; ++k) asm volatile("" : "+v"(w1r[k]));
    asm volatile("" : "+v"(b0r));
    asm volatile("" : "+v"(b1r));

    // stage out-MLP weights + zero accumulators
    for (int i = tid; i < 1024; i += 512) q0s[i] = ow0[(size_t)bid * 1024 + i];
    if (tid < 512) q1s[tid] = ow1[(size_t)bid * 512 + tid];
    if (tid < 32) { qb0s[tid] = ob0[bid * 32 + tid]; cnts[tid] = 0.f; }
    else if (tid < 48) qb1s[tid - 32] = ob1[bid * 16 + (tid - 32)];
    for (int i = tid; i < 32 * 33; i += 512) ((float*)acc)[i] = 0.f;
    __syncthreads();

    const int n = min(cursor[bid], CAP);
    for (int i = slot_id; i < n; i += 16) {
        const int p   = payload[bid * CAP + i];
        const int b   = p >> 16;
        const int row = p & 0xFFFF;

        float x[16];
        #pragma unroll
        for (int j = 0; j < 4; ++j) {
            float4 v = ((const float4*)(nf + (size_t)row * 16))[j];
            x[4*j] = v.x; x[4*j+1] = v.y; x[4*j+2] = v.z; x[4*j+3] = v.w;
        }
        float h = b0r;
        #pragma unroll
        for (int k = 0; k < 16; ++k) h = fmaf(w0r[k], x[k], h);
        h = fmaxf(h, 0.f);

        hbuf[wav][half * 32 + o] = h;          // same-wave LDS, in-order
        __builtin_amdgcn_wave_barrier();
        float a = b1r;
        #pragma unroll
        for (int j = 0; j < 8; ++j) {
            float4 v = ((const float4*)&hbuf[wav][half * 32])[j];
            a = fmaf(w1r[4*j],   v.x, a); a = fmaf(w1r[4*j+1], v.y, a);
            a = fmaf(w1r[4*j+2], v.z, a); a = fmaf(w1r[4*j+3], v.w, a);
        }
        __builtin_amdgcn_wave_barrier();
        a = fmaxf(a, 0.f);

        atomicAdd(&acc[b][o], a);              // (b+o)%32 banks: <=2-way
        if (o == 0) atomicAdd(&cnts[b], 1.f);
    }
    __syncthreads();

    // mean + out layer 0: thread t<256 -> batch b = t>>3, outputs 4*(t&7)..
    if (tid < 256) {
        const int b  = tid >> 3;
        const int o0 = (tid & 7) * 4;
        const float cv  = cnts[b];
        const float inv = cv > 0.f ? 1.0f / cv : 0.0f;
        #pragma unroll
        for (int j = 0; j < 4; ++j) {
            const int oo = o0 + j;
            float d = 0.f;
            #pragma unroll
            for (int k = 0; k < 32; ++k) d = fmaf(q0s[oo * 32 + k], acc[b][k], d);
            hb[b][oo] = fmaxf(fmaf(d, inv, qb0s[oo]), 0.f);
        }
    }
    __syncthreads();

    // out layer 1: thread t<256 -> batch b = t>>3, outputs 2*(t&7)..
    if (tid < 256) {
        const int b  = tid >> 3;
        const int o0 = (tid & 7) * 2;
        float r[2];
        #pragma unroll
        for (int j = 0; j < 2; ++j) {
            const int oo = o0 + j;
            float d = qb1s[oo];
            #pragma unroll
            for (int k = 0; k < 32; ++k) d = fmaf(q1s[oo * 32 + k], hb[b][k], d);
            r[j] = fmaxf(d, 0.f);
        }
        float2* op = (float2*)(out + ((size_t)b * NE_ + bid) * 16 + o0);
        *op = make_float2(r[0], r[1]);
    }
}

extern "C" void kernel_launch(void* const* d_in, const int* in_sizes, int n_in,
                              void* d_out, int out_size, void* d_ws, size_t ws_size,
                              hipStream_t stream) {
    const float* nf  = (const float*)d_in[0];
    const float* iw0 = (const float*)d_in[1];
    const float* ib0 = (const float*)d_in[2];
    const float* iw1 = (const float*)d_in[3];
    const float* ib1 = (const float*)d_in[4];
    const float* ow0 = (const float*)d_in[5];
    const float* ob0 = (const float*)d_in[6];
    const float* ow1 = (const float*)d_in[7];
    const float* ob1 = (const float*)d_in[8];
    const int*   inc = (const int*)d_in[9];

    int* cursor  = (int*)d_ws;
    int* payload = cursor + NE_;

    zero_cursor<<<2, 256, 0, stream>>>(cursor);
    scatter_kernel<<<(E_ + 1023) / 1024, 1024, 0, stream>>>(inc, cursor, payload);
    main_kernel<<<NE_, 512, 0, stream>>>(nf, iw0, ib0, iw1, ib1,
                                         ow0, ob0, ow1, ob1,
                                         cursor, payload, (float*)d_out);
}